// Round 1
// baseline (1222.016 us; speedup 1.0000x reference)
//
#include <hip/hip_runtime.h>
#include <stdint.h>

#define BATCH 8
#define C 128
#define TPB 512
#define ROWS_TILE 64
#define GEMM_BLOCKS 256

// order-preserving float -> uint key (monotone: a<b  <=>  key(a)<key(b))
__device__ __forceinline__ unsigned f2key(float f){
  unsigned b = __float_as_uint(f);
  return (b & 0x80000000u) ? ~b : (b | 0x80000000u);
}

// ---------------------------------------------------------------------------
// GEMM: h = relu(fea@W1+b1) -> out ; p = h@W2+b2 (f64 accum) -> pred ;
// segment max of key(p) over voxel ids via atomicMax.
// Persistent blocks, W1 + double-buffered fea tile in LDS (128KB).
// Lane owns column pair (2L, 2L+1); wave owns 8 rows of the 64-row tile.
// ---------------------------------------------------------------------------
__global__ __launch_bounds__(TPB) void k_gemm(
    const float* __restrict__ fea, const float* __restrict__ W1,
    const float* __restrict__ b1, const float* __restrict__ W2,
    const float* __restrict__ b2, const int* __restrict__ vox,
    float* __restrict__ out, float* __restrict__ pred,
    unsigned* __restrict__ segkey, int N)
{
  __shared__ float sW1[C * C];               // 64KB, [k][c] row-major as given
  __shared__ float sfea[2][ROWS_TILE * C];   // 2 x 32KB double buffer

  const int tid  = threadIdx.x;
  const int lane = tid & 63;
  const int wid  = tid >> 6;        // 0..7
  const int c0   = lane * 2;

  // stage W1 once (reused for all tiles this block processes)
  {
    const float4* src = (const float4*)W1;
    float4* dst = (float4*)sW1;
    #pragma unroll
    for (int i = 0; i < (C * C / 4) / TPB; ++i)
      dst[i * TPB + tid] = src[i * TPB + tid];
  }
  const float bb0 = b1[c0], bb1 = b1[c0 + 1];
  const float w20 = W2[c0], w21 = W2[c0 + 1];
  const double b2d = (double)b2[0];

  const int nTiles = N / ROWS_TILE;          // N % 64 == 0 (800000)
  int tile = blockIdx.x;
  const float4* feav = (const float4*)fea;
  float4 st[4];

  // prologue: load + write tile0
  if (tile < nTiles) {
    size_t base = (size_t)tile * (ROWS_TILE * C / 4);
    #pragma unroll
    for (int i = 0; i < 4; ++i) st[i] = feav[base + i * TPB + tid];
  }
  {
    float4* dst = (float4*)sfea[0];
    #pragma unroll
    for (int i = 0; i < 4; ++i) dst[i * TPB + tid] = st[i];
  }
  __syncthreads();

  int p = 0;
  for (; tile < nTiles; tile += GEMM_BLOCKS) {
    const int nxt = tile + GEMM_BLOCKS;
    const bool has = nxt < nTiles;
    if (has) {  // issue next-tile global loads early; latency hides under FMAs
      size_t base = (size_t)nxt * (ROWS_TILE * C / 4);
      #pragma unroll
      for (int i = 0; i < 4; ++i) st[i] = feav[base + i * TPB + tid];
    }

    const float* fr = &sfea[p][wid * 8 * C];   // this wave's 8 rows
    float a0[8], a1[8];
    #pragma unroll
    for (int j = 0; j < 8; ++j) { a0[j] = bb0; a1[j] = bb1; }

    for (int k = 0; k < C; k += 4) {
      float2 wA = *(const float2*)&sW1[(k + 0) * C + c0];
      float2 wB = *(const float2*)&sW1[(k + 1) * C + c0];
      float2 wC = *(const float2*)&sW1[(k + 2) * C + c0];
      float2 wD = *(const float2*)&sW1[(k + 3) * C + c0];
      #pragma unroll
      for (int j = 0; j < 8; ++j) {
        float4 f = *(const float4*)&fr[j * C + k];   // broadcast read
        a0[j] += f.x * wA.x; a1[j] += f.x * wA.y;
        a0[j] += f.y * wB.x; a1[j] += f.y * wB.y;
        a0[j] += f.z * wC.x; a1[j] += f.z * wC.y;
        a0[j] += f.w * wD.x; a1[j] += f.w * wD.y;
      }
    }

    #pragma unroll
    for (int j = 0; j < 8; ++j) {
      const int row = tile * ROWS_TILE + wid * 8 + j;
      const float h0 = fmaxf(a0[j], 0.f), h1 = fmaxf(a1[j], 0.f);
      *(float2*)&out[(size_t)row * C + c0] = make_float2(h0, h1);
      // pred in f64 to minimize ordering flips vs reference near the threshold
      double pd = (double)h0 * (double)w20 + (double)h1 * (double)w21;
      #pragma unroll
      for (int off = 32; off >= 1; off >>= 1) pd += __shfl_xor(pd, off, 64);
      if (lane == 0) {
        const float pv = (float)(pd + b2d);
        pred[row] = pv;
        atomicMax(&segkey[vox[row]], f2key(pv));
      }
    }

    __syncthreads();
    if (has) {
      float4* dst = (float4*)sfea[p ^ 1];
      #pragma unroll
      for (int i = 0; i < 4; ++i) dst[i * TPB + tid] = st[i];
    }
    __syncthreads();
    p ^= 1;
  }
}

// ---------------------------------------------------------------------------
// valkey[i] = (p_i is its voxel's max) ? 0xFFFFFFFF (= +inf slot) : key(p_i)
// + per-row histogram of high 16 key bits.
// ---------------------------------------------------------------------------
__global__ void k_mask_hist1(const float* __restrict__ pred,
                             const int* __restrict__ vox,
                             const unsigned* __restrict__ segkey,
                             unsigned* __restrict__ valkey,
                             unsigned* __restrict__ hist1, int N, int M)
{
  int i = blockIdx.x * blockDim.x + threadIdx.x;
  if (i >= N) return;
  unsigned kk = f2key(pred[i]);
  unsigned vk = (kk == segkey[vox[i]]) ? 0xFFFFFFFFu : kk;
  valkey[i] = vk;
  int row = i / M;
  atomicAdd(&hist1[row * 65536 + (vk >> 16)], 1u);
}

// pass2 histogram: low 16 bits, only elements inside the selected high bucket
__global__ void k_hist2(const unsigned* __restrict__ valkey,
                        unsigned* __restrict__ hist2,
                        const unsigned* __restrict__ sel, int N, int M)
{
  int i = blockIdx.x * blockDim.x + threadIdx.x;
  if (i >= N) return;
  unsigned vk = valkey[i];
  int row = i / M;
  if ((vk >> 16) == sel[row * 4 + 0])
    atomicAdd(&hist2[row * 65536 + (vk & 0xFFFFu)], 1u);
}

// ---------------------------------------------------------------------------
// radix-select scan: find smallest bin with cumulative count >= k.
// pass 0: hist1 -> sel[row] = {high bin, count strictly below it}
// pass 1: hist2 -> sel[row*4+2] = full 32-bit threshold key (sorted[k-1])
// ---------------------------------------------------------------------------
__global__ void k_scan(const unsigned* __restrict__ hist,
                       unsigned* __restrict__ sel,
                       const int* __restrict__ tnum, int M, int pass)
{
  const int row = blockIdx.x;
  const int t = threadIdx.x;  // 256 threads
  const unsigned* h = hist + (size_t)row * 65536;
  __shared__ unsigned part[256];
  unsigned s = 0;
  for (int i = 0; i < 256; ++i) s += h[t * 256 + i];
  part[t] = s;
  __syncthreads();
  if (t == 0) {
    const unsigned k = (unsigned)(M - tnum[0]);     // order-stat rank (1-based)
    unsigned cum = (pass == 0) ? 0u : sel[row * 4 + 1];
    int seg = 255;
    for (int i = 0; i < 256; ++i) {
      if (cum + part[i] >= k) { seg = i; break; }
      cum += part[i];
    }
    unsigned bin = 0;
    for (int i = 0; i < 256; ++i) {
      unsigned c = h[seg * 256 + i];
      if (cum + c >= k) { bin = (unsigned)(seg * 256 + i); break; }
      cum += c;
    }
    if (pass == 0) { sel[row * 4 + 0] = bin; sel[row * 4 + 1] = cum; }
    else           { sel[row * 4 + 2] = (sel[row * 4 + 0] << 16) | bin; }
  }
}

__global__ void k_scatter(const int* __restrict__ tidx, float* __restrict__ kt, int n)
{
  int i = blockIdx.x * blockDim.x + threadIdx.x;
  if (i < n) kt[tidx[i]] = 1.0f;
}

// zero rows that are not kept.  keep = (valkey > thr) | is_target
// (local maxima have valkey == 0xFFFFFFFF > thr, so auto-kept == "| ~mm")
__global__ __launch_bounds__(256) void k_final(const unsigned* __restrict__ valkey,
    const float* __restrict__ kt, const unsigned* __restrict__ sel,
    float* __restrict__ out, int N, int M)
{
  const int wid = threadIdx.x >> 6;
  const int lane = threadIdx.x & 63;
  const int r = blockIdx.x * 4 + wid;
  if (r >= N) return;
  unsigned vk = valkey[r];
  float kv = kt[r];
  unsigned thr = sel[(r / M) * 4 + 2];
  bool keep = (vk > thr) || (kv != 0.0f);
  if (!keep)
    *(float2*)&out[(size_t)r * C + lane * 2] = make_float2(0.f, 0.f);
}

// ---------------------------------------------------------------------------
extern "C" void kernel_launch(void* const* d_in, const int* in_sizes, int n_in,
                              void* d_out, int out_size, void* d_ws, size_t ws_size,
                              hipStream_t stream)
{
  const float* fea = (const float*)d_in[0];
  const float* W1  = (const float*)d_in[1];
  const float* b1  = (const float*)d_in[2];
  const float* W2  = (const float*)d_in[3];
  const float* b2  = (const float*)d_in[4];
  const int* vox   = (const int*)d_in[5];
  const int* tidx  = (const int*)d_in[6];
  const int* tnum  = (const int*)d_in[7];

  const int N = in_sizes[5];      // 800000
  const int M = N / BATCH;        // 100000
  const int nT = in_sizes[6];     // 400000

  float* out  = (float*)d_out;
  float* pred = out + (size_t)N * C;
  float* kt   = pred + N;

  // workspace layout
  char* w = (char*)d_ws;
  unsigned* segkey = (unsigned*)w;                                   // 512KB
  unsigned* hist1  = (unsigned*)(w + (512u << 10));                  // 2MB
  unsigned* hist2  = (unsigned*)(w + (512u << 10) + (2u << 20));     // 2MB
  unsigned* sel    = (unsigned*)(w + (512u << 10) + (4u << 20));     // 4KB
  unsigned* valkey = (unsigned*)(w + (512u << 10) + (4u << 20) + 4096u);

  const size_t zbytes = (512u << 10) + (4u << 20) + 4096u;
  hipMemsetAsync(d_ws, 0, zbytes, stream);
  hipMemsetAsync(kt, 0, (size_t)N * sizeof(float), stream);

  k_scatter<<<(nT + 255) / 256, 256, 0, stream>>>(tidx, kt, nT);
  k_gemm<<<GEMM_BLOCKS, TPB, 0, stream>>>(fea, W1, b1, W2, b2, vox,
                                          out, pred, segkey, N);
  k_mask_hist1<<<(N + 255) / 256, 256, 0, stream>>>(pred, vox, segkey,
                                                    valkey, hist1, N, M);
  k_scan<<<BATCH, 256, 0, stream>>>(hist1, sel, tnum, M, 0);
  k_hist2<<<(N + 255) / 256, 256, 0, stream>>>(valkey, hist2, sel, N, M);
  k_scan<<<BATCH, 256, 0, stream>>>(hist2, sel, tnum, M, 1);
  k_final<<<(N + 3) / 4, 256, 0, stream>>>(valkey, kt, sel, out, N, M);
}